// Round 10
// baseline (204.753 us; speedup 1.0000x reference)
//
#include <hip/hip_runtime.h>

// Problem constants (must match reference)
#define L_SZ 100000
#define K_DIM 128
#define B_SZ 16384
#define CS_SZ 8
#define NS_SZ 20
#define NEPOCH 10
#define LOG_SQRT_2PI 0.9189385332046727

#define CAP_T 40           // max referrals kept per tW row (Poisson mean 3.44)
#define CAP_C 24           // max referrals kept per cW row (Poisson mean 1.31)
#define NB    2048         // blocks for the sweep kernels (8192 waves)

typedef float f32x4 __attribute__((ext_vector_type(4)));

__device__ __forceinline__ float softplus_f(float x) {
    return fmaxf(x, 0.0f) + __logf(1.0f + __expf(-fabsf(x)));
}

// ---------------- workspace layout (bytes) ----------------
// [0)                cntT   : 100000 u32
// [400000)           cntC   : 100001 u32
// [800256)           ctx_sum: 16384*128 f32      (zeroed together with counts)
// [9188864)          entT   : 100000*CAP_T u32
// [25188864)         entC   : 100001*CAP_C u32
// [34788960)         ppB    : 2048 double (cW prior partials)
// [34805344)         ppT    : 2048 double (tW prior partials)
// [34821728)         pll    : 2048 double (likelihood partials)
#define OFF_CNTC   400000
#define OFF_CTXSUM 800256
#define OFF_ENTT   9188864
#define OFF_ENTC   25188864
#define OFF_PPB    34788960
#define OFF_PPT    34805344
#define OFF_PLL    34821728
#define WS_NEEDED  34838112
#define MEMSET_SPAN 9188864   // counts + pad + ctx_sum

// ---- build: scatter (b,ref) into per-row referral lists ---------------------
__global__ __launch_bounds__(256) void build_kernel(
    const int* __restrict__ contexts, const int* __restrict__ targets,
    const int* __restrict__ neg_idx,
    unsigned* __restrict__ cntT, unsigned* __restrict__ cntC,
    unsigned* __restrict__ entT, unsigned* __restrict__ entC)
{
    const int b = blockIdx.x * 256 + threadIdx.x;
    if (b >= B_SZ) return;

    const int t = targets[b];
    unsigned k = atomicAdd(&cntT[t], 1u);
    if (k < CAP_T) entT[(size_t)t * CAP_T + k] = ((unsigned)b << 1) | 1u;

    #pragma unroll
    for (int n = 0; n < NS_SZ; ++n) {
        const int r = neg_idx[b * NS_SZ + n];
        k = atomicAdd(&cntT[r], 1u);
        if (k < CAP_T) entT[(size_t)r * CAP_T + k] = ((unsigned)b << 1);
    }
    #pragma unroll
    for (int c = 0; c < CS_SZ; ++c) {
        const int r = contexts[b * CS_SZ + c];
        k = atomicAdd(&cntC[r], 1u);
        if (k < CAP_C) entC[(size_t)r * CAP_C + k] = (unsigned)b;
    }
}

// ---- pass B: sweep cW (sequential) -> prior sumsq + scatter rows into ctx_sum
// One wave per row (lane l holds dims 2l, 2l+1). 8192 waves grid-stride.
__global__ __launch_bounds__(256) void cw_kernel(
    const float* __restrict__ cW, const unsigned* __restrict__ cntC,
    const unsigned* __restrict__ entC, float* __restrict__ ctx_sum,
    double* __restrict__ ppB)
{
    const int lane = threadIdx.x & 63;
    const int wave = threadIdx.x >> 6;
    const int gw = __builtin_amdgcn_readfirstlane(blockIdx.x * 4 + wave);

    float pacc = 0.0f;
    for (int row = gw; row < L_SZ + 1; row += NB * 4) {
        const float2 v = *reinterpret_cast<const float2*>(
            &cW[(size_t)row * K_DIM + 2 * lane]);
        pacc += v.x * v.x + v.y * v.y;

        const unsigned cnt = min(cntC[row], (unsigned)CAP_C);  // wave-uniform
        for (unsigned i = 0; i < cnt; ++i) {
            const unsigned b = entC[(size_t)row * CAP_C + i];  // wave-uniform
            float* dst = &ctx_sum[(size_t)b * K_DIM + 2 * lane];
            atomicAdd(dst,     v.x);
            atomicAdd(dst + 1, v.y);
        }
    }

    #pragma unroll
    for (int o = 32; o; o >>= 1) pacc += __shfl_xor(pacc, o, 64);
    __shared__ float sp[4];
    if (lane == 0) sp[wave] = pacc;
    __syncthreads();
    if (threadIdx.x == 0)
        ppB[blockIdx.x] = (double)(sp[0] + sp[1] + sp[2] + sp[3]);
}

// ---- pass C: sweep tW (sequential) -> prior sumsq + dots vs ctx_sum + softplus
__global__ __launch_bounds__(256) void tw_kernel(
    const float* __restrict__ tW, const unsigned* __restrict__ cntT,
    const unsigned* __restrict__ entT, const float* __restrict__ ctx_sum,
    double* __restrict__ ppT, double* __restrict__ pll)
{
    const int lane = threadIdx.x & 63;
    const int wave = threadIdx.x >> 6;
    const int gw = __builtin_amdgcn_readfirstlane(blockIdx.x * 4 + wave);

    float pacc = 0.0f, lacc = 0.0f;
    for (int row = gw; row < L_SZ; row += NB * 4) {
        const float2 v = *reinterpret_cast<const float2*>(
            &tW[(size_t)row * K_DIM + 2 * lane]);
        pacc += v.x * v.x + v.y * v.y;

        const unsigned cnt = min(cntT[row], (unsigned)CAP_T);  // wave-uniform
        for (unsigned i = 0; i < cnt; ++i) {
            const unsigned e = entT[(size_t)row * CAP_T + i];  // wave-uniform
            const unsigned b = e >> 1;
            const float2 cs = *reinterpret_cast<const float2*>(
                &ctx_sum[(size_t)b * K_DIM + 2 * lane]);
            float p = v.x * cs.x + v.y * cs.y;
            #pragma unroll
            for (int o = 1; o <= 32; o <<= 1) p += __shfl_xor(p, o, 64);
            // e&1: positive target contributes softplus(-eta), else softplus(eta)
            const float sgn = (e & 1u) ? -1.0f : 1.0f;
            lacc += (lane == 0) ? softplus_f(sgn * p) : 0.0f;
        }
    }

    #pragma unroll
    for (int o = 32; o; o >>= 1) {
        pacc += __shfl_xor(pacc, o, 64);
        lacc += __shfl_xor(lacc, o, 64);
    }
    __shared__ float sp[4], sl[4];
    if (lane == 0) { sp[wave] = pacc; sl[wave] = lacc; }
    __syncthreads();
    if (threadIdx.x == 0) {
        ppT[blockIdx.x] = (double)(sp[0] + sp[1] + sp[2] + sp[3]);
        pll[blockIdx.x] = (double)(sl[0] + sl[1] + sl[2] + sl[3]);
    }
}

// ---- finalize ----------------------------------------------------------------
__global__ __launch_bounds__(256) void finalize_kernel(
    const double* __restrict__ ppB, const double* __restrict__ ppT,
    const double* __restrict__ pll, float* __restrict__ out)
{
    double a = 0.0, p = 0.0;
    for (int i = threadIdx.x; i < NB; i += 256) {
        a += pll[i];
        p += ppB[i] + ppT[i];
    }
    __shared__ double sA[256], sP[256];
    sA[threadIdx.x] = a; sP[threadIdx.x] = p;
    __syncthreads();
    for (int s = 128; s > 0; s >>= 1) {
        if (threadIdx.x < s) {
            sA[threadIdx.x] += sA[threadIdx.x + s];
            sP[threadIdx.x] += sP[threadIdx.x + s];
        }
        __syncthreads();
    }
    if (threadIdx.x == 0) {
        const double C = (double)((2LL * L_SZ + 1) * K_DIM) * LOG_SQRT_2PI;
        out[0] = (float)((double)NEPOCH * sA[0] + 0.5 * sP[0] + C);
    }
}

// ================= fallback path (R6, used only if ws too small) =============
__global__ __launch_bounds__(256) void fb_fused_kernel(
    const int* __restrict__ contexts, const int* __restrict__ targets,
    const int* __restrict__ neg_idx, const float* __restrict__ tW,
    const float* __restrict__ cW,
    double* __restrict__ pll, double* __restrict__ pprior)
{
    const int lane = threadIdx.x & 63;
    const int wave = threadIdx.x >> 6;
    const int j = lane & 15;
    const int g = lane >> 4;
    const int n_mine = 4 * j + g;
    const bool valid = (n_mine < 21);
    const float sgn = (n_mine == 0) ? -1.0f : 1.0f;
    const int b = __builtin_amdgcn_readfirstlane(blockIdx.x * 4 + wave);

    int ctxi[CS_SZ];
    #pragma unroll
    for (int c = 0; c < CS_SZ; ++c) ctxi[c] = contexts[b * CS_SZ + c];
    int tidx[6];
    #pragma unroll
    for (int s = 0; s < 6; ++s) {
        const int n = 4 * s + g;
        int t = 0;
        if (n == 0)       t = targets[b];
        else if (n < 21)  t = neg_idx[b * NS_SZ + (n - 1)];
        tidx[s] = t;
    }
    float4 s0 = {0,0,0,0}, s1 = {0,0,0,0};
    #pragma unroll
    for (int c = 0; c < CS_SZ; ++c) {
        const float* base = &cW[(size_t)ctxi[c] * K_DIM];
        const float4 a = *reinterpret_cast<const float4*>(base + 4 * j);
        const float4 d = *reinterpret_cast<const float4*>(base + 64 + 4 * j);
        s0.x += a.x; s0.y += a.y; s0.z += a.z; s0.w += a.w;
        s1.x += d.x; s1.y += d.y; s1.z += d.z; s1.w += d.w;
    }
    float keep = 0.0f;
    #pragma unroll
    for (int s = 0; s < 6; ++s) {
        const float* base = &tW[(size_t)tidx[s] * K_DIM];
        const float4 a = *reinterpret_cast<const float4*>(base + 4 * j);
        const float4 d = *reinterpret_cast<const float4*>(base + 64 + 4 * j);
        float p = a.x * s0.x + a.y * s0.y + a.z * s0.z + a.w * s0.w
                + d.x * s1.x + d.y * s1.y + d.z * s1.z + d.w * s1.w;
        p += __shfl_xor(p, 1, 16); p += __shfl_xor(p, 2, 16);
        p += __shfl_xor(p, 4, 16); p += __shfl_xor(p, 8, 16);
        keep = (j == s) ? p : keep;
    }
    float lacc = valid ? softplus_f(sgn * keep) : 0.0f;

    const int NT4 = (L_SZ * K_DIM) / 4, NC4 = ((L_SZ + 1) * K_DIM) / 4;
    const int tid = blockIdx.x * blockDim.x + threadIdx.x;
    const int stride = gridDim.x * blockDim.x;
    float pacc = 0.0f;
    const f32x4* t4 = reinterpret_cast<const f32x4*>(tW);
    for (int i = tid; i < NT4; i += stride) {
        const f32x4 v = t4[i];
        pacc += v.x * v.x + v.y * v.y + v.z * v.z + v.w * v.w;
    }
    const f32x4* c4 = reinterpret_cast<const f32x4*>(cW);
    for (int i = tid; i < NC4; i += stride) {
        const f32x4 v = c4[i];
        pacc += v.x * v.x + v.y * v.y + v.z * v.z + v.w * v.w;
    }
    #pragma unroll
    for (int o = 32; o; o >>= 1) {
        lacc += __shfl_xor(lacc, o, 64);
        pacc += __shfl_xor(pacc, o, 64);
    }
    __shared__ float sl[4], sp[4];
    if (lane == 0) { sl[wave] = lacc; sp[wave] = pacc; }
    __syncthreads();
    if (threadIdx.x == 0) {
        pll[blockIdx.x]    = (double)(sl[0] + sl[1] + sl[2] + sl[3]);
        pprior[blockIdx.x] = (double)(sp[0] + sp[1] + sp[2] + sp[3]);
    }
}

__global__ __launch_bounds__(256) void fb_finalize_kernel(
    const double* __restrict__ pll, const double* __restrict__ pprior,
    int n, float* __restrict__ out)
{
    double a = 0.0, p = 0.0;
    for (int i = threadIdx.x; i < n; i += 256) { a += pll[i]; p += pprior[i]; }
    __shared__ double sA[256], sP[256];
    sA[threadIdx.x] = a; sP[threadIdx.x] = p;
    __syncthreads();
    for (int s = 128; s > 0; s >>= 1) {
        if (threadIdx.x < s) {
            sA[threadIdx.x] += sA[threadIdx.x + s];
            sP[threadIdx.x] += sP[threadIdx.x + s];
        }
        __syncthreads();
    }
    if (threadIdx.x == 0) {
        const double C = (double)((2LL * L_SZ + 1) * K_DIM) * LOG_SQRT_2PI;
        out[0] = (float)((double)NEPOCH * sA[0] + 0.5 * sP[0] + C);
    }
}

extern "C" void kernel_launch(void* const* d_in, const int* in_sizes, int n_in,
                              void* d_out, int out_size, void* d_ws, size_t ws_size,
                              hipStream_t stream) {
    const int*   contexts = (const int*)d_in[0];
    const int*   targets  = (const int*)d_in[1];
    const int*   neg_idx  = (const int*)d_in[2];
    const float* tW       = (const float*)d_in[3];
    const float* cW       = (const float*)d_in[4];
    float* out = (float*)d_out;
    char* ws = (char*)d_ws;

    if (ws_size >= (size_t)WS_NEEDED) {
        unsigned* cntT    = (unsigned*)(ws);
        unsigned* cntC    = (unsigned*)(ws + OFF_CNTC);
        float*    ctx_sum = (float*)   (ws + OFF_CTXSUM);
        unsigned* entT    = (unsigned*)(ws + OFF_ENTT);
        unsigned* entC    = (unsigned*)(ws + OFF_ENTC);
        double*   ppB     = (double*)  (ws + OFF_PPB);
        double*   ppT     = (double*)  (ws + OFF_PPT);
        double*   pll     = (double*)  (ws + OFF_PLL);

        // zero counts + ctx_sum every call (graph-capture legal)
        hipMemsetAsync(ws, 0, MEMSET_SPAN, stream);

        build_kernel<<<(B_SZ + 255) / 256, 256, 0, stream>>>(
            contexts, targets, neg_idx, cntT, cntC, entT, entC);
        cw_kernel<<<NB, 256, 0, stream>>>(cW, cntC, entC, ctx_sum, ppB);
        tw_kernel<<<NB, 256, 0, stream>>>(tW, cntT, entT, ctx_sum, ppT, pll);
        finalize_kernel<<<1, 256, 0, stream>>>(ppB, ppT, pll, out);
    } else {
        // fallback: direct-gather path (R6)
        double* pll    = (double*)d_ws;
        double* pprior = pll + 4096;
        fb_fused_kernel<<<4096, 256, 0, stream>>>(contexts, targets, neg_idx,
                                                  tW, cW, pll, pprior);
        fb_finalize_kernel<<<1, 256, 0, stream>>>(pll, pprior, 4096, out);
    }
}